// Round 3
// baseline (670.401 us; speedup 1.0000x reference)
//
#include <hip/hip_runtime.h>
#include <hip/hip_bf16.h>
#include <math.h>

#define NSEQ 384
#define DPAIR 128
#define NHEAD 4
#define CDIM 32
#define KCH 192          // key-chunk size (2 chunks of 192)
#define OSTR 136         // k_out LDS row stride (128 ch + 8 pad, 16B-aligned)

typedef short bf16x8 __attribute__((ext_vector_type(8)));
typedef float f32x4 __attribute__((ext_vector_type(4)));

__device__ __forceinline__ short f2b(float f) {
    __hip_bfloat16 b = __float2bfloat16(f);
    return __builtin_bit_cast(short, b);
}
__device__ __forceinline__ float b2f(short s) {
    unsigned int u = ((unsigned int)(unsigned short)s) << 16;
    return __builtin_bit_cast(float, u);
}

// ---------------------------------------------------------------------------
// Kernel 1: LayerNorm (fp32 exact) -> Z bf16, and pair bias (fp32)
// ---------------------------------------------------------------------------
__global__ __launch_bounds__(256) void k_ln(
    const float* __restrict__ Zraw, const float* __restrict__ gamma,
    const float* __restrict__ beta, const float* __restrict__ bw,
    __hip_bfloat16* __restrict__ Zb, float* __restrict__ biasT)
{
    const int wave = threadIdx.x >> 6, lane = threadIdx.x & 63;
    const int pos = blockIdx.x * 4 + wave;
    const float2 z = *(const float2*)(Zraw + (size_t)pos * DPAIR + lane * 2);
    float s = z.x + z.y, sq = z.x * z.x + z.y * z.y;
#pragma unroll
    for (int o = 32; o; o >>= 1) { s += __shfl_xor(s, o); sq += __shfl_xor(sq, o); }
    const float mu = s * (1.f / 128.f);
    const float rstd = rsqrtf(sq * (1.f / 128.f) - mu * mu + 1e-5f);
    const int c0 = lane * 2;
    const float z0 = (z.x - mu) * rstd * gamma[c0] + beta[c0];
    const float z1 = (z.y - mu) * rstd * gamma[c0 + 1] + beta[c0 + 1];
    __hip_bfloat162 hz;
    hz.x = __float2bfloat16(z0);
    hz.y = __float2bfloat16(z1);
    *(__hip_bfloat162*)(Zb + (size_t)pos * DPAIR + c0) = hz;
#pragma unroll
    for (int h = 0; h < NHEAD; h++) {
        float p = z0 * bw[c0 * NHEAD + h] + z1 * bw[(c0 + 1) * NHEAD + h];
#pragma unroll
        for (int o = 32; o; o >>= 1) p += __shfl_xor(p, o);
        if (lane == 0) biasT[(size_t)h * NSEQ * NSEQ + pos] = p;
    }
}

// ---------------------------------------------------------------------------
// Kernel 2: transpose weights to [out][in] bf16. order: Wq,Wk,Wv,Wg,Wo
// ---------------------------------------------------------------------------
__global__ __launch_bounds__(256) void k_wt(
    const float* __restrict__ Wq, const float* __restrict__ Wk,
    const float* __restrict__ Wv, const float* __restrict__ Wg,
    const float* __restrict__ Wo, __hip_bfloat16* __restrict__ WT)
{
    const int m = blockIdx.y;
    const float* src = (m == 0) ? Wq : (m == 1) ? Wk : (m == 2) ? Wv : (m == 3) ? Wg : Wo;
    const int idx = blockIdx.x * 256 + threadIdx.x;
    const int in = idx >> 7, out = idx & 127;
    WT[m * 16384 + out * 128 + in] = __float2bfloat16(src[idx]);
}

// ---------------------------------------------------------------------------
// Kernel 3: fused projections + flash attention, one block per (row i, head h)
// 256 threads = 4 waves.  LDS = 58,880 B.
// ---------------------------------------------------------------------------
__global__ __launch_bounds__(256) void k_attn(
    const __hip_bfloat16* __restrict__ Zb,   // [N*N][128]
    const __hip_bfloat16* __restrict__ WT,   // 5 x [128][128] (out-major)
    const float* __restrict__ biasT,         // [4][N][N]
    __hip_bfloat16* __restrict__ Ob)         // [N*N][128]
{
    __shared__ short Ks[KCH * 40];           // [192][40]
    __shared__ short Vt[CDIM * 200];         // [32][200] (V transposed)
    __shared__ short Qst[4][16 * 40];        // per-wave Q staging tile
    __shared__ short Ps[4][16 * 200];        // per-wave P chunk

    const int i = blockIdx.x, h = blockIdx.y;
    const int tid = threadIdx.x, wave = tid >> 6, lane = tid & 63;
    const int lr = lane & 15, lg = lane >> 4;
    const short* Zrow = (const short*)Zb + (size_t)i * NSEQ * DPAIR;
    const short* WQ = (const short*)WT + 0 * 16384 + (h * CDIM) * DPAIR;
    const short* WK = (const short*)WT + 1 * 16384 + (h * CDIM) * DPAIR;
    const short* WV = (const short*)WT + 2 * 16384 + (h * CDIM) * DPAIR;

    // ---- Q phase: this wave's 6 q-strips -> register A-fragments ----
    bf16x8 qreg[6];
    short* Qw = Qst[wave];
#pragma unroll
    for (int s = 0; s < 6; ++s) {
        const int q0 = wave * 96 + s * 16;
        f32x4 a0 = {0.f, 0.f, 0.f, 0.f}, a1 = {0.f, 0.f, 0.f, 0.f};
#pragma unroll
        for (int ks = 0; ks < 4; ks++) {
            bf16x8 afr = *(const bf16x8*)(Zrow + (q0 + lr) * DPAIR + ks * 32 + lg * 8);
            bf16x8 b0 = *(const bf16x8*)(WQ + lr * DPAIR + ks * 32 + lg * 8);
            bf16x8 b1 = *(const bf16x8*)(WQ + (16 + lr) * DPAIR + ks * 32 + lg * 8);
            a0 = __builtin_amdgcn_mfma_f32_16x16x32_bf16(afr, b0, a0, 0, 0, 0);
            a1 = __builtin_amdgcn_mfma_f32_16x16x32_bf16(afr, b1, a1, 0, 0, 0);
        }
#pragma unroll
        for (int j = 0; j < 4; j++) {
            Qw[(lg * 4 + j) * 40 + lr]      = f2b(a0[j]);
            Qw[(lg * 4 + j) * 40 + 16 + lr] = f2b(a1[j]);
        }
        asm volatile("s_waitcnt lgkmcnt(0)" ::: "memory");
        qreg[s] = *(const bf16x8*)(Qw + lr * 40 + lg * 8);
        asm volatile("" ::: "memory");
    }

    // ---- online-softmax state ----
    float m_run[6][4], l_run[6][4];
    f32x4 oacc[6][2];
#pragma unroll
    for (int s = 0; s < 6; s++) {
#pragma unroll
        for (int j = 0; j < 4; j++) { m_run[s][j] = -1e30f; l_run[s][j] = 0.f; }
        oacc[s][0] = (f32x4){0.f, 0.f, 0.f, 0.f};
        oacc[s][1] = (f32x4){0.f, 0.f, 0.f, 0.f};
    }

    const float scale = 0.17677669529663689f;   // 1/sqrt(32)
    short* Pw = Ps[wave];

#pragma unroll
    for (int c = 0; c < 2; c++) {
        __syncthreads();   // protect Ks/Vt from overwrite while prior chunk in use
        // ---- K/V projection for keys [c*192, c*192+192) ----
        for (int t3 = 0; t3 < 3; t3++) {
            const int jt = wave * 3 + t3;          // tile within chunk (0..11)
            const int jg = c * KCH + jt * 16;      // global key row
            bf16x8 afr[4];
#pragma unroll
            for (int ks = 0; ks < 4; ks++)
                afr[ks] = *(const bf16x8*)(Zrow + (jg + lr) * DPAIR + ks * 32 + lg * 8);
#pragma unroll
            for (int mat = 0; mat < 2; mat++) {
                const short* WB = mat ? WV : WK;
#pragma unroll
                for (int nt = 0; nt < 2; nt++) {
                    f32x4 acc = {0.f, 0.f, 0.f, 0.f};
#pragma unroll
                    for (int ks = 0; ks < 4; ks++) {
                        bf16x8 bfr = *(const bf16x8*)(WB + (nt * 16 + lr) * DPAIR + ks * 32 + lg * 8);
                        acc = __builtin_amdgcn_mfma_f32_16x16x32_bf16(afr[ks], bfr, acc, 0, 0, 0);
                    }
#pragma unroll
                    for (int j = 0; j < 4; j++) {
                        const int rl = jt * 16 + lg * 4 + j;   // local key row
                        const int col = nt * 16 + lr;
                        const short v = f2b(acc[j]);
                        if (mat == 0) Ks[rl * 40 + col] = v;
                        else          Vt[col * 200 + rl] = v;
                    }
                }
            }
        }
        __syncthreads();

        // ---- attention over this chunk, 6 strips per wave ----
#pragma unroll
        for (int s = 0; s < 6; s++) {
            const int q0 = wave * 96 + s * 16;
            f32x4 sacc[12];
#pragma unroll
            for (int t = 0; t < 12; t++) {
                bf16x8 kfr = *(const bf16x8*)(Ks + (t * 16 + lr) * 40 + lg * 8);
                f32x4 z = {0.f, 0.f, 0.f, 0.f};
                sacc[t] = __builtin_amdgcn_mfma_f32_16x16x32_bf16(qreg[s], kfr, z, 0, 0, 0);
            }
            float pm[4], sum[4];
#pragma unroll
            for (int j = 0; j < 4; j++) pm[j] = m_run[s][j];
            const float* bp = biasT + ((size_t)h * NSEQ + q0 + lg * 4) * NSEQ + c * KCH;
#pragma unroll
            for (int t = 0; t < 12; t++) {
#pragma unroll
                for (int j = 0; j < 4; j++) {
                    const float v = sacc[t][j] * scale + bp[j * NSEQ + t * 16 + lr];
                    sacc[t][j] = v;
                    pm[j] = fmaxf(pm[j], v);
                }
            }
#pragma unroll
            for (int j = 0; j < 4; j++) {
#pragma unroll
                for (int o = 1; o < 16; o <<= 1) pm[j] = fmaxf(pm[j], __shfl_xor(pm[j], o));
                sum[j] = 0.f;
            }
#pragma unroll
            for (int t = 0; t < 12; t++) {
#pragma unroll
                for (int j = 0; j < 4; j++) {
                    const float p = __expf(sacc[t][j] - pm[j]);
                    sum[j] += p;
                    Pw[(lg * 4 + j) * 200 + t * 16 + lr] = f2b(p);
                }
            }
#pragma unroll
            for (int j = 0; j < 4; j++) {
#pragma unroll
                for (int o = 1; o < 16; o <<= 1) sum[j] += __shfl_xor(sum[j], o);
            }
            float fs[4];
#pragma unroll
            for (int j = 0; j < 4; j++) {
                fs[j] = __expf(m_run[s][j] - pm[j]);       // 0 at c==0 (m_run=-1e30)
                l_run[s][j] = l_run[s][j] * fs[j] + sum[j];
                m_run[s][j] = pm[j];
            }
#pragma unroll
            for (int nt = 0; nt < 2; nt++)
#pragma unroll
                for (int j = 0; j < 4; j++) oacc[s][nt][j] *= fs[j];
            asm volatile("s_waitcnt lgkmcnt(0)" ::: "memory");
#pragma unroll
            for (int nt = 0; nt < 2; nt++) {
#pragma unroll
                for (int ks = 0; ks < 6; ks++) {
                    bf16x8 pfr = *(const bf16x8*)(Pw + lr * 200 + ks * 32 + lg * 8);
                    bf16x8 vfr = *(const bf16x8*)(Vt + (nt * 16 + lr) * 200 + ks * 32 + lg * 8);
                    oacc[s][nt] = __builtin_amdgcn_mfma_f32_16x16x32_bf16(pfr, vfr, oacc[s][nt], 0, 0, 0);
                }
            }
        }
    }

    // ---- store O ----
#pragma unroll
    for (int s = 0; s < 6; s++) {
        const int q0 = wave * 96 + s * 16;
#pragma unroll
        for (int nt = 0; nt < 2; nt++) {
#pragma unroll
            for (int j = 0; j < 4; j++) {
                const size_t row = (size_t)i * NSEQ + q0 + lg * 4 + j;
                Ob[row * DPAIR + h * CDIM + nt * 16 + lr] =
                    __float2bfloat16(oacc[s][nt][j] / l_run[s][j]);
            }
        }
    }
}

// ---------------------------------------------------------------------------
// Kernel 4: gate + output projection + residual.  64 positions per block.
// LDS row stride OSTR=136 (>=128 channels!  72 was the round-1/2 bug).
// ---------------------------------------------------------------------------
__global__ __launch_bounds__(256) void k_out(
    const float* __restrict__ Zraw,
    const __hip_bfloat16* __restrict__ Zb,
    const __hip_bfloat16* __restrict__ Ob,
    const __hip_bfloat16* __restrict__ WT,
    const float* __restrict__ bg,
    const float* __restrict__ out_bias,
    float* __restrict__ out)
{
    __shared__ short Zt[64 * OSTR];
    __shared__ short GOt[64 * OSTR];
    const int pos0 = blockIdx.x * 64;
    const int tid = threadIdx.x, wave = tid >> 6, lane = tid & 63;
    const int lr = lane & 15, lg = lane >> 4;

#pragma unroll
    for (int it = 0; it < 4; ++it) {
        const int cidx = tid + 256 * it;
        const int row = cidx >> 4, cc = (cidx & 15) * 8;
        *(bf16x8*)(Zt + row * OSTR + cc) =
            *(const bf16x8*)((const short*)Zb + (size_t)(pos0 + row) * DPAIR + cc);
    }
    __syncthreads();

    const short* WgT = (const short*)WT + 3 * 16384;
    const short* WoT = (const short*)WT + 4 * 16384;
    const int m0 = wave * 16;

    bf16x8 afr[4];
#pragma unroll
    for (int ks = 0; ks < 4; ks++)
        afr[ks] = *(const bf16x8*)(Zt + (m0 + lr) * OSTR + ks * 32 + lg * 8);
#pragma unroll
    for (int nt = 0; nt < 8; nt++) {
        f32x4 acc = {0.f, 0.f, 0.f, 0.f};
#pragma unroll
        for (int ks = 0; ks < 4; ks++) {
            bf16x8 bfr = *(const bf16x8*)(WgT + (nt * 16 + lr) * DPAIR + ks * 32 + lg * 8);
            acc = __builtin_amdgcn_mfma_f32_16x16x32_bf16(afr[ks], bfr, acc, 0, 0, 0);
        }
        const int col = nt * 16 + lr;
        const float bgv = bg[col];
#pragma unroll
        for (int j = 0; j < 4; j++) {
            const int row = m0 + lg * 4 + j;
            const float g = 1.f / (1.f + __expf(-(acc[j] + bgv)));
            const float ov = b2f(((const short*)Ob)[(size_t)(pos0 + row) * DPAIR + col]);
            GOt[row * OSTR + col] = f2b(g * ov);
        }
    }
    __syncthreads();

#pragma unroll
    for (int ks = 0; ks < 4; ks++)
        afr[ks] = *(const bf16x8*)(GOt + (m0 + lr) * OSTR + ks * 32 + lg * 8);
#pragma unroll
    for (int nt = 0; nt < 8; nt++) {
        f32x4 acc = {0.f, 0.f, 0.f, 0.f};
#pragma unroll
        for (int ks = 0; ks < 4; ks++) {
            bf16x8 bfr = *(const bf16x8*)(WoT + (nt * 16 + lr) * DPAIR + ks * 32 + lg * 8);
            acc = __builtin_amdgcn_mfma_f32_16x16x32_bf16(afr[ks], bfr, acc, 0, 0, 0);
        }
        const int col = nt * 16 + lr;
        const float ob = out_bias[col];
#pragma unroll
        for (int j = 0; j < 4; j++) {
            const size_t idx = (size_t)(pos0 + m0 + lg * 4 + j) * DPAIR + col;
            out[idx] = Zraw[idx] + acc[j] + ob;
        }
    }
}

// ---------------------------------------------------------------------------
extern "C" void kernel_launch(void* const* d_in, const int* in_sizes, int n_in,
                              void* d_out, int out_size, void* d_ws, size_t ws_size,
                              hipStream_t stream)
{
    const float* Zraw     = (const float*)d_in[0];
    const float* gamma    = (const float*)d_in[1];
    const float* beta     = (const float*)d_in[2];
    const float* bw       = (const float*)d_in[3];
    const float* Wq       = (const float*)d_in[4];
    const float* Wk       = (const float*)d_in[5];
    const float* Wv       = (const float*)d_in[6];
    const float* Wg       = (const float*)d_in[7];
    const float* bg       = (const float*)d_in[8];
    const float* Wo       = (const float*)d_in[9];
    const float* out_bias = (const float*)d_in[10];

    char* ws = (char*)d_ws;
    const size_t zbytes = (size_t)NSEQ * NSEQ * DPAIR * 2;
    __hip_bfloat16* Zb    = (__hip_bfloat16*)ws;
    __hip_bfloat16* Ob    = (__hip_bfloat16*)(ws + zbytes);
    float*          biasT = (float*)(ws + 2 * zbytes);
    __hip_bfloat16* WT    = (__hip_bfloat16*)(ws + 2 * zbytes + (size_t)NHEAD * NSEQ * NSEQ * 4);

    k_ln<<<NSEQ * NSEQ / 4, 256, 0, stream>>>(Zraw, gamma, beta, bw, Zb, biasT);
    k_wt<<<dim3(64, 5), 256, 0, stream>>>(Wq, Wk, Wv, Wg, Wo, WT);
    k_attn<<<dim3(NSEQ, NHEAD), 256, 0, stream>>>(Zb, WT, biasT, Ob);
    k_out<<<NSEQ * NSEQ / 64, 256, 0, stream>>>(Zraw, Zb, Ob, WT, bg, out_bias, (float*)d_out);
}

// Round 4
// 623.584 us; speedup vs baseline: 1.0751x; 1.0751x over previous
//
#include <hip/hip_runtime.h>
#include <hip/hip_bf16.h>
#include <math.h>

#define NSEQ 384
#define DPAIR 128
#define NHEAD 4
#define CDIM 32
#define KCH 128          // key-chunk size (3 chunks of 128)
#define PSTR 152         // P / Vt LDS row stride (2-way bank max, 16B-aligned)
#define OSTR 136         // k_out LDS row stride

typedef short bf16x8 __attribute__((ext_vector_type(8)));
typedef float f32x4 __attribute__((ext_vector_type(4)));

__device__ __forceinline__ short f2b(float f) {
    __hip_bfloat16 b = __float2bfloat16(f);
    return __builtin_bit_cast(short, b);
}
__device__ __forceinline__ float b2f(short s) {
    unsigned int u = ((unsigned int)(unsigned short)s) << 16;
    return __builtin_bit_cast(float, u);
}

// ---------------------------------------------------------------------------
// Kernel 1: LayerNorm (fp32 exact) -> Z bf16, and pair bias (fp32) in the
// per-lane permuted layout consumed by k_attn:
//   idx(h,q,k): sg=q>>4, lg=(q&15)>>2, j=q&3; c=k>>7, kc=k&127, t=kc>>4, lr=kc&15
//   flat = ((h*24+sg)*3 + c)*2048 + (lg*16+lr)*32 + t*4 + j
// ---------------------------------------------------------------------------
__global__ __launch_bounds__(256) void k_ln(
    const float* __restrict__ Zraw, const float* __restrict__ gamma,
    const float* __restrict__ beta, const float* __restrict__ bw,
    __hip_bfloat16* __restrict__ Zb, float* __restrict__ bias_perm)
{
    const int wave = threadIdx.x >> 6, lane = threadIdx.x & 63;
    const int pos = blockIdx.x * 4 + wave;
    const float2 z = *(const float2*)(Zraw + (size_t)pos * DPAIR + lane * 2);
    float s = z.x + z.y, sq = z.x * z.x + z.y * z.y;
#pragma unroll
    for (int o = 32; o; o >>= 1) { s += __shfl_xor(s, o); sq += __shfl_xor(sq, o); }
    const float mu = s * (1.f / 128.f);
    const float rstd = rsqrtf(sq * (1.f / 128.f) - mu * mu + 1e-5f);
    const int c0 = lane * 2;
    const float z0 = (z.x - mu) * rstd * gamma[c0] + beta[c0];
    const float z1 = (z.y - mu) * rstd * gamma[c0 + 1] + beta[c0 + 1];
    __hip_bfloat162 hz;
    hz.x = __float2bfloat16(z0);
    hz.y = __float2bfloat16(z1);
    *(__hip_bfloat162*)(Zb + (size_t)pos * DPAIR + c0) = hz;

    const int q = pos / NSEQ, k = pos - q * NSEQ;
    const int sg = q >> 4, lg = (q & 15) >> 2, j = q & 3;
    const int c = k >> 7, kc = k & 127, t = kc >> 4, lr = kc & 15;
    const size_t flat = ((size_t)((0 * 24 + sg) * 3 + c)) * 2048 + (lg * 16 + lr) * 32 + t * 4 + j;
    const size_t hstride = (size_t)24 * 3 * 2048;
#pragma unroll
    for (int h = 0; h < NHEAD; h++) {
        float p = z0 * bw[c0 * NHEAD + h] + z1 * bw[(c0 + 1) * NHEAD + h];
#pragma unroll
        for (int o = 32; o; o >>= 1) p += __shfl_xor(p, o);
        if (lane == 0) bias_perm[flat + h * hstride] = p;
    }
}

// ---------------------------------------------------------------------------
// Kernel 2: transpose weights to [out][in] bf16. order: Wq,Wk,Wv,Wg,Wo
// ---------------------------------------------------------------------------
__global__ __launch_bounds__(256) void k_wt(
    const float* __restrict__ Wq, const float* __restrict__ Wk,
    const float* __restrict__ Wv, const float* __restrict__ Wg,
    const float* __restrict__ Wo, __hip_bfloat16* __restrict__ WT)
{
    const int m = blockIdx.y;
    const float* src = (m == 0) ? Wq : (m == 1) ? Wk : (m == 2) ? Wv : (m == 3) ? Wg : Wo;
    const int idx = blockIdx.x * 256 + threadIdx.x;
    const int in = idx >> 7, out = idx & 127;
    WT[m * 16384 + out * 128 + in] = __float2bfloat16(src[idx]);
}

// ---------------------------------------------------------------------------
// Kernel 3: fused projections + flash attention, one block per (row i, head h)
// 512 threads = 8 waves, 3 q-strips/wave, 3 key-chunks of 128.
// LDS = 69,120 B -> 2 blocks/CU; VGPR capped <=128 -> 4 waves/SIMD.
// ---------------------------------------------------------------------------
__global__ __launch_bounds__(512, 4) void k_attn(
    const __hip_bfloat16* __restrict__ Zb,   // [N*N][128]
    const __hip_bfloat16* __restrict__ WT,   // 5 x [128][128] (out-major)
    const float* __restrict__ bias_perm,     // permuted, see k_ln
    __hip_bfloat16* __restrict__ Ob)         // [N*N][128]
{
    __shared__ short Ks[KCH * 40];           // [128][40]
    __shared__ short Vt[CDIM * PSTR];        // [32][152] (V transposed)
    __shared__ short Qst[8][16 * 40];        // per-wave Q staging tile
    __shared__ short Ps[8][16 * PSTR];       // per-wave P chunk [16][152]

    const int i = blockIdx.x, h = blockIdx.y;
    const int tid = threadIdx.x, wave = tid >> 6, lane = tid & 63;
    const int lr = lane & 15, lg = lane >> 4;
    const short* Zrow = (const short*)Zb + (size_t)i * NSEQ * DPAIR;
    const short* WQ = (const short*)WT + 0 * 16384 + (h * CDIM) * DPAIR;
    const short* WK = (const short*)WT + 1 * 16384 + (h * CDIM) * DPAIR;
    const short* WV = (const short*)WT + 2 * 16384 + (h * CDIM) * DPAIR;

    // ---- Q phase: this wave's 3 q-strips -> register A-fragments ----
    bf16x8 qreg[3];
    short* Qw = Qst[wave];
#pragma unroll
    for (int s = 0; s < 3; ++s) {
        const int q0 = wave * 48 + s * 16;
        f32x4 a0 = {0.f, 0.f, 0.f, 0.f}, a1 = {0.f, 0.f, 0.f, 0.f};
#pragma unroll
        for (int ks = 0; ks < 4; ks++) {
            bf16x8 afr = *(const bf16x8*)(Zrow + (q0 + lr) * DPAIR + ks * 32 + lg * 8);
            bf16x8 b0 = *(const bf16x8*)(WQ + lr * DPAIR + ks * 32 + lg * 8);
            bf16x8 b1 = *(const bf16x8*)(WQ + (16 + lr) * DPAIR + ks * 32 + lg * 8);
            a0 = __builtin_amdgcn_mfma_f32_16x16x32_bf16(afr, b0, a0, 0, 0, 0);
            a1 = __builtin_amdgcn_mfma_f32_16x16x32_bf16(afr, b1, a1, 0, 0, 0);
        }
#pragma unroll
        for (int j = 0; j < 4; j++) {
            Qw[(lg * 4 + j) * 40 + lr]      = f2b(a0[j]);
            Qw[(lg * 4 + j) * 40 + 16 + lr] = f2b(a1[j]);
        }
        asm volatile("s_waitcnt lgkmcnt(0)" ::: "memory");
        qreg[s] = *(const bf16x8*)(Qw + lr * 40 + lg * 8);
        asm volatile("" ::: "memory");
    }

    // ---- online-softmax state ----
    float m_run[3][4], l_run[3][4];
    f32x4 oacc[3][2];
#pragma unroll
    for (int s = 0; s < 3; s++) {
#pragma unroll
        for (int j = 0; j < 4; j++) { m_run[s][j] = -1e30f; l_run[s][j] = 0.f; }
        oacc[s][0] = (f32x4){0.f, 0.f, 0.f, 0.f};
        oacc[s][1] = (f32x4){0.f, 0.f, 0.f, 0.f};
    }

    const float scale = 0.17677669529663689f;   // 1/sqrt(32)
    short* Pw = Ps[wave];

    for (int c = 0; c < 3; c++) {
        __syncthreads();   // protect Ks/Vt while prior chunk in use
        // ---- K/V projection for keys [c*128, c*128+128): 1 tile per wave ----
        {
            const int jt = wave;                   // tile within chunk (0..7)
            const int jg = c * KCH + jt * 16;      // global key row
            bf16x8 afr[4];
#pragma unroll
            for (int ks = 0; ks < 4; ks++)
                afr[ks] = *(const bf16x8*)(Zrow + (jg + lr) * DPAIR + ks * 32 + lg * 8);
#pragma unroll
            for (int mat = 0; mat < 2; mat++) {
                const short* WB = mat ? WV : WK;
#pragma unroll
                for (int nt = 0; nt < 2; nt++) {
                    f32x4 acc = {0.f, 0.f, 0.f, 0.f};
#pragma unroll
                    for (int ks = 0; ks < 4; ks++) {
                        bf16x8 bfr = *(const bf16x8*)(WB + (nt * 16 + lr) * DPAIR + ks * 32 + lg * 8);
                        acc = __builtin_amdgcn_mfma_f32_16x16x32_bf16(afr[ks], bfr, acc, 0, 0, 0);
                    }
#pragma unroll
                    for (int j = 0; j < 4; j++) {
                        const int rl = jt * 16 + lg * 4 + j;   // local key row
                        const int col = nt * 16 + lr;
                        const short v = f2b(acc[j]);
                        if (mat == 0) Ks[rl * 40 + col] = v;
                        else          Vt[col * PSTR + rl] = v;
                    }
                }
            }
        }
        __syncthreads();

        // ---- attention over this chunk, 3 strips per wave ----
#pragma unroll
        for (int s = 0; s < 3; s++) {
            const int sg = wave * 3 + s;           // global strip id (q0 = sg*16)
            f32x4 sacc[8];
#pragma unroll
            for (int t = 0; t < 8; t++) {
                bf16x8 kfr = *(const bf16x8*)(Ks + (t * 16 + lr) * 40 + lg * 8);
                f32x4 z = {0.f, 0.f, 0.f, 0.f};
                sacc[t] = __builtin_amdgcn_mfma_f32_16x16x32_bf16(qreg[s], kfr, z, 0, 0, 0);
            }
            // coalesced bias: 8 float4 per lane (pre-permuted layout)
            const float* bbase = bias_perm + ((size_t)(h * 24 + sg) * 3 + c) * 2048 + lane * 32;
            float4 bt[8];
#pragma unroll
            for (int t = 0; t < 8; t++) bt[t] = *(const float4*)(bbase + t * 4);

            float pm[4], sum[4];
#pragma unroll
            for (int j = 0; j < 4; j++) pm[j] = m_run[s][j];
#pragma unroll
            for (int t = 0; t < 8; t++) {
                const float* btp = (const float*)&bt[t];
#pragma unroll
                for (int j = 0; j < 4; j++) {
                    const float v = sacc[t][j] * scale + btp[j];
                    sacc[t][j] = v;
                    pm[j] = fmaxf(pm[j], v);
                }
            }
#pragma unroll
            for (int j = 0; j < 4; j++) {
#pragma unroll
                for (int o = 1; o < 16; o <<= 1) pm[j] = fmaxf(pm[j], __shfl_xor(pm[j], o));
                sum[j] = 0.f;
            }
#pragma unroll
            for (int t = 0; t < 8; t++) {
#pragma unroll
                for (int j = 0; j < 4; j++) {
                    const float p = __expf(sacc[t][j] - pm[j]);
                    sum[j] += p;
                    Pw[(lg * 4 + j) * PSTR + t * 16 + lr] = f2b(p);
                }
            }
#pragma unroll
            for (int j = 0; j < 4; j++) {
#pragma unroll
                for (int o = 1; o < 16; o <<= 1) sum[j] += __shfl_xor(sum[j], o);
            }
            float fs[4];
#pragma unroll
            for (int j = 0; j < 4; j++) {
                fs[j] = __expf(m_run[s][j] - pm[j]);       // 0 at c==0
                l_run[s][j] = l_run[s][j] * fs[j] + sum[j];
                m_run[s][j] = pm[j];
            }
#pragma unroll
            for (int nt = 0; nt < 2; nt++)
#pragma unroll
                for (int j = 0; j < 4; j++) oacc[s][nt][j] *= fs[j];
            asm volatile("s_waitcnt lgkmcnt(0)" ::: "memory");
#pragma unroll
            for (int nt = 0; nt < 2; nt++) {
#pragma unroll
                for (int ks = 0; ks < 4; ks++) {
                    bf16x8 pfr = *(const bf16x8*)(Pw + lr * PSTR + ks * 32 + lg * 8);
                    bf16x8 vfr = *(const bf16x8*)(Vt + (nt * 16 + lr) * PSTR + ks * 32 + lg * 8);
                    oacc[s][nt] = __builtin_amdgcn_mfma_f32_16x16x32_bf16(pfr, vfr, oacc[s][nt], 0, 0, 0);
                }
            }
        }
    }

    // ---- store O ----
#pragma unroll
    for (int s = 0; s < 3; s++) {
        const int q0 = wave * 48 + s * 16;
#pragma unroll
        for (int nt = 0; nt < 2; nt++) {
#pragma unroll
            for (int j = 0; j < 4; j++) {
                const size_t row = (size_t)i * NSEQ + q0 + lg * 4 + j;
                Ob[row * DPAIR + h * CDIM + nt * 16 + lr] =
                    __float2bfloat16(oacc[s][nt][j] / l_run[s][j]);
            }
        }
    }
}

// ---------------------------------------------------------------------------
// Kernel 4: gate + output projection + residual.  64 positions per block.
// ---------------------------------------------------------------------------
__global__ __launch_bounds__(256) void k_out(
    const float* __restrict__ Zraw,
    const __hip_bfloat16* __restrict__ Zb,
    const __hip_bfloat16* __restrict__ Ob,
    const __hip_bfloat16* __restrict__ WT,
    const float* __restrict__ bg,
    const float* __restrict__ out_bias,
    float* __restrict__ out)
{
    __shared__ short Zt[64 * OSTR];
    __shared__ short GOt[64 * OSTR];
    const int pos0 = blockIdx.x * 64;
    const int tid = threadIdx.x, wave = tid >> 6, lane = tid & 63;
    const int lr = lane & 15, lg = lane >> 4;

#pragma unroll
    for (int it = 0; it < 4; ++it) {
        const int cidx = tid + 256 * it;
        const int row = cidx >> 4, cc = (cidx & 15) * 8;
        *(bf16x8*)(Zt + row * OSTR + cc) =
            *(const bf16x8*)((const short*)Zb + (size_t)(pos0 + row) * DPAIR + cc);
    }
    __syncthreads();

    const short* WgT = (const short*)WT + 3 * 16384;
    const short* WoT = (const short*)WT + 4 * 16384;
    const int m0 = wave * 16;

    bf16x8 afr[4];
#pragma unroll
    for (int ks = 0; ks < 4; ks++)
        afr[ks] = *(const bf16x8*)(Zt + (m0 + lr) * OSTR + ks * 32 + lg * 8);
#pragma unroll
    for (int nt = 0; nt < 8; nt++) {
        f32x4 acc = {0.f, 0.f, 0.f, 0.f};
#pragma unroll
        for (int ks = 0; ks < 4; ks++) {
            bf16x8 bfr = *(const bf16x8*)(WgT + (nt * 16 + lr) * DPAIR + ks * 32 + lg * 8);
            acc = __builtin_amdgcn_mfma_f32_16x16x32_bf16(afr[ks], bfr, acc, 0, 0, 0);
        }
        const int col = nt * 16 + lr;
        const float bgv = bg[col];
#pragma unroll
        for (int j = 0; j < 4; j++) {
            const int row = m0 + lg * 4 + j;
            const float g = 1.f / (1.f + __expf(-(acc[j] + bgv)));
            const float ov = b2f(((const short*)Ob)[(size_t)(pos0 + row) * DPAIR + col]);
            GOt[row * OSTR + col] = f2b(g * ov);
        }
    }
    __syncthreads();

#pragma unroll
    for (int ks = 0; ks < 4; ks++)
        afr[ks] = *(const bf16x8*)(GOt + (m0 + lr) * OSTR + ks * 32 + lg * 8);
#pragma unroll
    for (int nt = 0; nt < 8; nt++) {
        f32x4 acc = {0.f, 0.f, 0.f, 0.f};
#pragma unroll
        for (int ks = 0; ks < 4; ks++) {
            bf16x8 bfr = *(const bf16x8*)(WoT + (nt * 16 + lr) * DPAIR + ks * 32 + lg * 8);
            acc = __builtin_amdgcn_mfma_f32_16x16x32_bf16(afr[ks], bfr, acc, 0, 0, 0);
        }
        const int col = nt * 16 + lr;
        const float ob = out_bias[col];
#pragma unroll
        for (int j = 0; j < 4; j++) {
            const size_t idx = (size_t)(pos0 + m0 + lg * 4 + j) * DPAIR + col;
            out[idx] = Zraw[idx] + acc[j] + ob;
        }
    }
}

// ---------------------------------------------------------------------------
extern "C" void kernel_launch(void* const* d_in, const int* in_sizes, int n_in,
                              void* d_out, int out_size, void* d_ws, size_t ws_size,
                              hipStream_t stream)
{
    const float* Zraw     = (const float*)d_in[0];
    const float* gamma    = (const float*)d_in[1];
    const float* beta     = (const float*)d_in[2];
    const float* bw       = (const float*)d_in[3];
    const float* Wq       = (const float*)d_in[4];
    const float* Wk       = (const float*)d_in[5];
    const float* Wv       = (const float*)d_in[6];
    const float* Wg       = (const float*)d_in[7];
    const float* bg       = (const float*)d_in[8];
    const float* Wo       = (const float*)d_in[9];
    const float* out_bias = (const float*)d_in[10];

    char* ws = (char*)d_ws;
    const size_t zbytes = (size_t)NSEQ * NSEQ * DPAIR * 2;
    __hip_bfloat16* Zb        = (__hip_bfloat16*)ws;
    __hip_bfloat16* Ob        = (__hip_bfloat16*)(ws + zbytes);
    float*          bias_perm = (float*)(ws + 2 * zbytes);
    __hip_bfloat16* WT        = (__hip_bfloat16*)(ws + 2 * zbytes + (size_t)NHEAD * NSEQ * NSEQ * 4);

    k_ln<<<NSEQ * NSEQ / 4, 256, 0, stream>>>(Zraw, gamma, beta, bw, Zb, bias_perm);
    k_wt<<<dim3(64, 5), 256, 0, stream>>>(Wq, Wk, Wv, Wg, Wo, WT);
    k_attn<<<dim3(NSEQ, NHEAD), 512, 0, stream>>>(Zb, WT, bias_perm, Ob);
    k_out<<<NSEQ * NSEQ / 64, 256, 0, stream>>>(Zraw, Zb, Ob, WT, bg, out_bias, (float*)d_out);
}

// Round 5
// 526.455 us; speedup vs baseline: 1.2734x; 1.1845x over previous
//
#include <hip/hip_runtime.h>
#include <hip/hip_bf16.h>
#include <math.h>

#define NSEQ 384
#define DPAIR 128
#define NHEAD 4
#define CDIM 32
#define KCH 128          // key-chunk size (3 chunks of 128)
#define PSTR 152         // P / Vt LDS row stride (16B-aligned)
#define OSTR 136         // k_out LDS row stride

typedef short bf16x8 __attribute__((ext_vector_type(8)));
typedef float f32x4 __attribute__((ext_vector_type(4)));

__device__ __forceinline__ short f2b(float f) {
    __hip_bfloat16 b = __float2bfloat16(f);
    return __builtin_bit_cast(short, b);
}
__device__ __forceinline__ float b2f(short s) {
    unsigned int u = ((unsigned int)(unsigned short)s) << 16;
    return __builtin_bit_cast(float, u);
}

// ---------------------------------------------------------------------------
// Kernel 1: LayerNorm (fp32 exact) -> Z bf16, and pair bias (fp32) in the
// per-lane permuted layout consumed by k_attn:
//   idx(h,q,k): sg=q>>4, lg=(q&15)>>2, j=q&3; c=k>>7, kc=k&127, t=kc>>4, lr=kc&15
//   flat = ((h*24+sg)*3 + c)*2048 + (lg*16+lr)*32 + t*4 + j
// ---------------------------------------------------------------------------
__global__ __launch_bounds__(256) void k_ln(
    const float* __restrict__ Zraw, const float* __restrict__ gamma,
    const float* __restrict__ beta, const float* __restrict__ bw,
    __hip_bfloat16* __restrict__ Zb, float* __restrict__ bias_perm)
{
    const int wave = threadIdx.x >> 6, lane = threadIdx.x & 63;
    const int pos = blockIdx.x * 4 + wave;
    const float2 z = *(const float2*)(Zraw + (size_t)pos * DPAIR + lane * 2);
    float s = z.x + z.y, sq = z.x * z.x + z.y * z.y;
#pragma unroll
    for (int o = 32; o; o >>= 1) { s += __shfl_xor(s, o); sq += __shfl_xor(sq, o); }
    const float mu = s * (1.f / 128.f);
    const float rstd = rsqrtf(sq * (1.f / 128.f) - mu * mu + 1e-5f);
    const int c0 = lane * 2;
    const float z0 = (z.x - mu) * rstd * gamma[c0] + beta[c0];
    const float z1 = (z.y - mu) * rstd * gamma[c0 + 1] + beta[c0 + 1];
    __hip_bfloat162 hz;
    hz.x = __float2bfloat16(z0);
    hz.y = __float2bfloat16(z1);
    *(__hip_bfloat162*)(Zb + (size_t)pos * DPAIR + c0) = hz;

    const int q = pos / NSEQ, k = pos - q * NSEQ;
    const int sg = q >> 4, lg = (q & 15) >> 2, j = q & 3;
    const int c = k >> 7, kc = k & 127, t = kc >> 4, lr = kc & 15;
    const size_t flat = ((size_t)(sg * 3 + c)) * 2048 + (lg * 16 + lr) * 32 + t * 4 + j;
    const size_t hstride = (size_t)24 * 3 * 2048;
#pragma unroll
    for (int h = 0; h < NHEAD; h++) {
        float p = z0 * bw[c0 * NHEAD + h] + z1 * bw[(c0 + 1) * NHEAD + h];
#pragma unroll
        for (int o = 32; o; o >>= 1) p += __shfl_xor(p, o);
        if (lane == 0) bias_perm[flat + h * hstride] = p;
    }
}

// ---------------------------------------------------------------------------
// Kernel 2: transpose weights to [out][in] bf16. order: Wq,Wk,Wv,Wg,Wo
// ---------------------------------------------------------------------------
__global__ __launch_bounds__(256) void k_wt(
    const float* __restrict__ Wq, const float* __restrict__ Wk,
    const float* __restrict__ Wv, const float* __restrict__ Wg,
    const float* __restrict__ Wo, __hip_bfloat16* __restrict__ WT)
{
    const int m = blockIdx.y;
    const float* src = (m == 0) ? Wq : (m == 1) ? Wk : (m == 2) ? Wv : (m == 3) ? Wg : Wo;
    const int idx = blockIdx.x * 256 + threadIdx.x;
    const int in = idx >> 7, out = idx & 127;
    WT[m * 16384 + out * 128 + in] = __float2bfloat16(src[idx]);
}

// ---------------------------------------------------------------------------
// Kernel 3: fused projections + flash attention, one block per (row i, head h)
// 512 threads = 8 waves, 3 q-strips/wave, 3 key-chunks of 128.
// LDS = 69,120 B -> 2 blocks/CU.  launch_bounds(512,2): VGPR cap 256 so the
// allocator does NOT spill (round-4's (512,4) forced 64 VGPR -> ~0.9 GB of
// scratch HBM traffic).  Target: ~120 VGPR -> 4 waves/SIMD.
// ---------------------------------------------------------------------------
__global__ __launch_bounds__(512, 2) void k_attn(
    const __hip_bfloat16* __restrict__ Zb,   // [N*N][128]
    const __hip_bfloat16* __restrict__ WT,   // 5 x [128][128] (out-major)
    const float* __restrict__ bias_perm,     // permuted, see k_ln
    __hip_bfloat16* __restrict__ Ob)         // [N*N][128]
{
    __shared__ short Ks[KCH * 40];           // [128][40]
    __shared__ short Vt[CDIM * PSTR];        // [32][152] (V transposed)
    __shared__ short Qst[8][16 * 40];        // per-wave Q staging tile
    __shared__ short Ps[8][16 * PSTR];       // per-wave P chunk [16][152]

    const int i = blockIdx.x, h = blockIdx.y;
    const int tid = threadIdx.x, wave = tid >> 6, lane = tid & 63;
    const int lr = lane & 15, lg = lane >> 4;
    const short* Zrow = (const short*)Zb + (size_t)i * NSEQ * DPAIR;
    const short* WQ = (const short*)WT + 0 * 16384 + (h * CDIM) * DPAIR;
    const short* WK = (const short*)WT + 1 * 16384 + (h * CDIM) * DPAIR;
    const short* WV = (const short*)WT + 2 * 16384 + (h * CDIM) * DPAIR;

    // ---- Q phase: this wave's 3 q-strips -> register A-fragments ----
    bf16x8 qreg[3];
    short* Qw = Qst[wave];
#pragma unroll
    for (int s = 0; s < 3; ++s) {
        const int q0 = wave * 48 + s * 16;
        f32x4 a0 = {0.f, 0.f, 0.f, 0.f}, a1 = {0.f, 0.f, 0.f, 0.f};
#pragma unroll
        for (int ks = 0; ks < 4; ks++) {
            bf16x8 afr = *(const bf16x8*)(Zrow + (q0 + lr) * DPAIR + ks * 32 + lg * 8);
            bf16x8 b0 = *(const bf16x8*)(WQ + lr * DPAIR + ks * 32 + lg * 8);
            bf16x8 b1 = *(const bf16x8*)(WQ + (16 + lr) * DPAIR + ks * 32 + lg * 8);
            a0 = __builtin_amdgcn_mfma_f32_16x16x32_bf16(afr, b0, a0, 0, 0, 0);
            a1 = __builtin_amdgcn_mfma_f32_16x16x32_bf16(afr, b1, a1, 0, 0, 0);
        }
#pragma unroll
        for (int j = 0; j < 4; j++) {
            Qw[(lg * 4 + j) * 40 + lr]      = f2b(a0[j]);
            Qw[(lg * 4 + j) * 40 + 16 + lr] = f2b(a1[j]);
        }
        asm volatile("s_waitcnt lgkmcnt(0)" ::: "memory");
        qreg[s] = *(const bf16x8*)(Qw + lr * 40 + lg * 8);
        asm volatile("" ::: "memory");
    }

    // ---- online-softmax state ----
    float m_run[3][4], l_run[3][4];
    f32x4 oacc[3][2];
#pragma unroll
    for (int s = 0; s < 3; s++) {
#pragma unroll
        for (int j = 0; j < 4; j++) { m_run[s][j] = -1e30f; l_run[s][j] = 0.f; }
        oacc[s][0] = (f32x4){0.f, 0.f, 0.f, 0.f};
        oacc[s][1] = (f32x4){0.f, 0.f, 0.f, 0.f};
    }

    const float scale = 0.17677669529663689f;   // 1/sqrt(32)
    short* Pw = Ps[wave];

    for (int c = 0; c < 3; c++) {
        __syncthreads();   // protect Ks/Vt while prior chunk in use
        // ---- K/V projection for keys [c*128, c*128+128): 1 tile per wave ----
        {
            const int jt = wave;                   // tile within chunk (0..7)
            const int jg = c * KCH + jt * 16;      // global key row
            bf16x8 afr[4];
#pragma unroll
            for (int ks = 0; ks < 4; ks++)
                afr[ks] = *(const bf16x8*)(Zrow + (jg + lr) * DPAIR + ks * 32 + lg * 8);
#pragma unroll
            for (int mat = 0; mat < 2; mat++) {
                const short* WB = mat ? WV : WK;
#pragma unroll
                for (int nt = 0; nt < 2; nt++) {
                    f32x4 acc = {0.f, 0.f, 0.f, 0.f};
#pragma unroll
                    for (int ks = 0; ks < 4; ks++) {
                        bf16x8 bfr = *(const bf16x8*)(WB + (nt * 16 + lr) * DPAIR + ks * 32 + lg * 8);
                        acc = __builtin_amdgcn_mfma_f32_16x16x32_bf16(afr[ks], bfr, acc, 0, 0, 0);
                    }
#pragma unroll
                    for (int j = 0; j < 4; j++) {
                        const int rl = jt * 16 + lg * 4 + j;   // local key row
                        const int col = nt * 16 + lr;
                        const short v = f2b(acc[j]);
                        if (mat == 0) Ks[rl * 40 + col] = v;
                        else          Vt[col * PSTR + rl] = v;
                    }
                }
            }
        }
        __syncthreads();

        // ---- attention over this chunk, 3 strips per wave ----
#pragma unroll
        for (int s = 0; s < 3; s++) {
            const int sg = wave * 3 + s;           // global strip id (q0 = sg*16)
            f32x4 sacc[8];
#pragma unroll
            for (int t = 0; t < 8; t++) {
                bf16x8 kfr = *(const bf16x8*)(Ks + (t * 16 + lr) * 40 + lg * 8);
                f32x4 z = {0.f, 0.f, 0.f, 0.f};
                sacc[t] = __builtin_amdgcn_mfma_f32_16x16x32_bf16(qreg[s], kfr, z, 0, 0, 0);
            }
            const float* bbase = bias_perm + ((size_t)(h * 24 + sg) * 3 + c) * 2048 + lane * 32;

            float pm[4], sum[4];
#pragma unroll
            for (int j = 0; j < 4; j++) pm[j] = m_run[s][j];
            // bias in two batches of 4 float4 (16 regs peak, not 32)
#pragma unroll
            for (int tb = 0; tb < 2; tb++) {
                float4 bt[4];
#pragma unroll
                for (int u = 0; u < 4; u++) bt[u] = *(const float4*)(bbase + (tb * 4 + u) * 4);
#pragma unroll
                for (int u = 0; u < 4; u++) {
                    const int t = tb * 4 + u;
                    const float* btp = (const float*)&bt[u];
#pragma unroll
                    for (int j = 0; j < 4; j++) {
                        const float v = sacc[t][j] * scale + btp[j];
                        sacc[t][j] = v;
                        pm[j] = fmaxf(pm[j], v);
                    }
                }
            }
#pragma unroll
            for (int j = 0; j < 4; j++) {
#pragma unroll
                for (int o = 1; o < 16; o <<= 1) pm[j] = fmaxf(pm[j], __shfl_xor(pm[j], o));
                sum[j] = 0.f;
            }
#pragma unroll
            for (int t = 0; t < 8; t++) {
#pragma unroll
                for (int j = 0; j < 4; j++) {
                    const float p = __expf(sacc[t][j] - pm[j]);
                    sum[j] += p;
                    Pw[(lg * 4 + j) * PSTR + t * 16 + lr] = f2b(p);
                }
            }
#pragma unroll
            for (int j = 0; j < 4; j++) {
#pragma unroll
                for (int o = 1; o < 16; o <<= 1) sum[j] += __shfl_xor(sum[j], o);
            }
            float fs[4];
#pragma unroll
            for (int j = 0; j < 4; j++) {
                fs[j] = __expf(m_run[s][j] - pm[j]);       // 0 at c==0
                l_run[s][j] = l_run[s][j] * fs[j] + sum[j];
                m_run[s][j] = pm[j];
            }
#pragma unroll
            for (int nt = 0; nt < 2; nt++)
#pragma unroll
                for (int j = 0; j < 4; j++) oacc[s][nt][j] *= fs[j];
            asm volatile("s_waitcnt lgkmcnt(0)" ::: "memory");
#pragma unroll
            for (int nt = 0; nt < 2; nt++) {
#pragma unroll
                for (int ks = 0; ks < 4; ks++) {
                    bf16x8 pfr = *(const bf16x8*)(Pw + lr * PSTR + ks * 32 + lg * 8);
                    bf16x8 vfr = *(const bf16x8*)(Vt + (nt * 16 + lr) * PSTR + ks * 32 + lg * 8);
                    oacc[s][nt] = __builtin_amdgcn_mfma_f32_16x16x32_bf16(pfr, vfr, oacc[s][nt], 0, 0, 0);
                }
            }
        }
    }

    // ---- store O ----
#pragma unroll
    for (int s = 0; s < 3; s++) {
        const int q0 = wave * 48 + s * 16;
#pragma unroll
        for (int nt = 0; nt < 2; nt++) {
#pragma unroll
            for (int j = 0; j < 4; j++) {
                const size_t row = (size_t)i * NSEQ + q0 + lg * 4 + j;
                Ob[row * DPAIR + h * CDIM + nt * 16 + lr] =
                    __float2bfloat16(oacc[s][nt][j] / l_run[s][j]);
            }
        }
    }
}

// ---------------------------------------------------------------------------
// Kernel 4: gate + output projection + residual.  64 positions per block.
// ---------------------------------------------------------------------------
__global__ __launch_bounds__(256) void k_out(
    const float* __restrict__ Zraw,
    const __hip_bfloat16* __restrict__ Zb,
    const __hip_bfloat16* __restrict__ Ob,
    const __hip_bfloat16* __restrict__ WT,
    const float* __restrict__ bg,
    const float* __restrict__ out_bias,
    float* __restrict__ out)
{
    __shared__ short Zt[64 * OSTR];
    __shared__ short GOt[64 * OSTR];
    const int pos0 = blockIdx.x * 64;
    const int tid = threadIdx.x, wave = tid >> 6, lane = tid & 63;
    const int lr = lane & 15, lg = lane >> 4;

#pragma unroll
    for (int it = 0; it < 4; ++it) {
        const int cidx = tid + 256 * it;
        const int row = cidx >> 4, cc = (cidx & 15) * 8;
        *(bf16x8*)(Zt + row * OSTR + cc) =
            *(const bf16x8*)((const short*)Zb + (size_t)(pos0 + row) * DPAIR + cc);
    }
    __syncthreads();

    const short* WgT = (const short*)WT + 3 * 16384;
    const short* WoT = (const short*)WT + 4 * 16384;
    const int m0 = wave * 16;

    bf16x8 afr[4];
#pragma unroll
    for (int ks = 0; ks < 4; ks++)
        afr[ks] = *(const bf16x8*)(Zt + (m0 + lr) * OSTR + ks * 32 + lg * 8);
#pragma unroll
    for (int nt = 0; nt < 8; nt++) {
        f32x4 acc = {0.f, 0.f, 0.f, 0.f};
#pragma unroll
        for (int ks = 0; ks < 4; ks++) {
            bf16x8 bfr = *(const bf16x8*)(WgT + (nt * 16 + lr) * DPAIR + ks * 32 + lg * 8);
            acc = __builtin_amdgcn_mfma_f32_16x16x32_bf16(afr[ks], bfr, acc, 0, 0, 0);
        }
        const int col = nt * 16 + lr;
        const float bgv = bg[col];
#pragma unroll
        for (int j = 0; j < 4; j++) {
            const int row = m0 + lg * 4 + j;
            const float g = 1.f / (1.f + __expf(-(acc[j] + bgv)));
            const float ov = b2f(((const short*)Ob)[(size_t)(pos0 + row) * DPAIR + col]);
            GOt[row * OSTR + col] = f2b(g * ov);
        }
    }
    __syncthreads();

#pragma unroll
    for (int ks = 0; ks < 4; ks++)
        afr[ks] = *(const bf16x8*)(GOt + (m0 + lr) * OSTR + ks * 32 + lg * 8);
#pragma unroll
    for (int nt = 0; nt < 8; nt++) {
        f32x4 acc = {0.f, 0.f, 0.f, 0.f};
#pragma unroll
        for (int ks = 0; ks < 4; ks++) {
            bf16x8 bfr = *(const bf16x8*)(WoT + (nt * 16 + lr) * DPAIR + ks * 32 + lg * 8);
            acc = __builtin_amdgcn_mfma_f32_16x16x32_bf16(afr[ks], bfr, acc, 0, 0, 0);
        }
        const int col = nt * 16 + lr;
        const float ob = out_bias[col];
#pragma unroll
        for (int j = 0; j < 4; j++) {
            const size_t idx = (size_t)(pos0 + m0 + lg * 4 + j) * DPAIR + col;
            out[idx] = Zraw[idx] + acc[j] + ob;
        }
    }
}

// ---------------------------------------------------------------------------
extern "C" void kernel_launch(void* const* d_in, const int* in_sizes, int n_in,
                              void* d_out, int out_size, void* d_ws, size_t ws_size,
                              hipStream_t stream)
{
    const float* Zraw     = (const float*)d_in[0];
    const float* gamma    = (const float*)d_in[1];
    const float* beta     = (const float*)d_in[2];
    const float* bw       = (const float*)d_in[3];
    const float* Wq       = (const float*)d_in[4];
    const float* Wk       = (const float*)d_in[5];
    const float* Wv       = (const float*)d_in[6];
    const float* Wg       = (const float*)d_in[7];
    const float* bg       = (const float*)d_in[8];
    const float* Wo       = (const float*)d_in[9];
    const float* out_bias = (const float*)d_in[10];

    char* ws = (char*)d_ws;
    const size_t zbytes = (size_t)NSEQ * NSEQ * DPAIR * 2;
    __hip_bfloat16* Zb        = (__hip_bfloat16*)ws;
    __hip_bfloat16* Ob        = (__hip_bfloat16*)(ws + zbytes);
    float*          bias_perm = (float*)(ws + 2 * zbytes);
    __hip_bfloat16* WT        = (__hip_bfloat16*)(ws + 2 * zbytes + (size_t)NHEAD * NSEQ * NSEQ * 4);

    k_ln<<<NSEQ * NSEQ / 4, 256, 0, stream>>>(Zraw, gamma, beta, bw, Zb, bias_perm);
    k_wt<<<dim3(64, 5), 256, 0, stream>>>(Wq, Wk, Wv, Wg, Wo, WT);
    k_attn<<<dim3(NSEQ, NHEAD), 512, 0, stream>>>(Zb, WT, bias_perm, Ob);
    k_out<<<NSEQ * NSEQ / 64, 256, 0, stream>>>(Zraw, Zb, Ob, WT, bg, out_bias, (float*)d_out);
}

// Round 6
// 461.908 us; speedup vs baseline: 1.4514x; 1.1397x over previous
//
#include <hip/hip_runtime.h>
#include <hip/hip_bf16.h>
#include <math.h>

#define NSEQ 384
#define DPAIR 128
#define NHEAD 4
#define CDIM 32
#define KCH 128          // key-chunk size (3 chunks of 128)
#define VSTR 136         // Vt LDS row stride (elems)
#define OSTR 152         // k_out LDS row stride (76 dwords -> spread banks)

typedef short bf16x8 __attribute__((ext_vector_type(8)));
typedef short bf16x4 __attribute__((ext_vector_type(4)));
typedef float f32x4 __attribute__((ext_vector_type(4)));

__device__ __forceinline__ short f2b(float f) {
    __hip_bfloat16 b = __float2bfloat16(f);
    return __builtin_bit_cast(short, b);
}
__device__ __forceinline__ float b2f(short s) {
    unsigned int u = ((unsigned int)(unsigned short)s) << 16;
    return __builtin_bit_cast(float, u);
}

// 16x16x16 bf16 MFMA via inline asm (ISA-verified; compiler doesn't pad
// hazards around asm, so lead with s_nop 1 for VALU->MFMA src safety).
__device__ __forceinline__ void mfma16(f32x4& acc, bf16x4 a, bf16x4 b) {
    asm("s_nop 1\n\tv_mfma_f32_16x16x16_bf16 %0, %1, %2, %0"
        : "+v"(acc) : "v"(a), "v"(b));
}

// ---------------------------------------------------------------------------
// Kernel 1: LayerNorm (fp32 exact) -> Z bf16, and pair bias (fp32) permuted
// for the SWAPPED-QK lane mapping: lane holds S^T[k=16t+4lg+j][q=lr]:
//   q: sg=q>>4, lr=q&15 ;  k: c=k>>7, kc=k&127, t=kc>>4, lg=(kc>>2)&3, j=kc&3
//   flat = ((h*24+sg)*3 + c)*2048 + (lg*16+lr)*32 + t*4 + j
// ---------------------------------------------------------------------------
__global__ __launch_bounds__(256) void k_ln(
    const float* __restrict__ Zraw, const float* __restrict__ gamma,
    const float* __restrict__ beta, const float* __restrict__ bw,
    __hip_bfloat16* __restrict__ Zb, float* __restrict__ bias_perm)
{
    const int wave = threadIdx.x >> 6, lane = threadIdx.x & 63;
    const int pos = blockIdx.x * 4 + wave;
    const float2 z = *(const float2*)(Zraw + (size_t)pos * DPAIR + lane * 2);
    float s = z.x + z.y, sq = z.x * z.x + z.y * z.y;
#pragma unroll
    for (int o = 32; o; o >>= 1) { s += __shfl_xor(s, o); sq += __shfl_xor(sq, o); }
    const float mu = s * (1.f / 128.f);
    const float rstd = rsqrtf(sq * (1.f / 128.f) - mu * mu + 1e-5f);
    const int c0 = lane * 2;
    const float z0 = (z.x - mu) * rstd * gamma[c0] + beta[c0];
    const float z1 = (z.y - mu) * rstd * gamma[c0 + 1] + beta[c0 + 1];
    __hip_bfloat162 hz;
    hz.x = __float2bfloat16(z0);
    hz.y = __float2bfloat16(z1);
    *(__hip_bfloat162*)(Zb + (size_t)pos * DPAIR + c0) = hz;

    const int q = pos / NSEQ, k = pos - q * NSEQ;
    const int sg = q >> 4, lrq = q & 15;
    const int c = k >> 7, kc = k & 127, t = kc >> 4, lgk = (kc >> 2) & 3, j = kc & 3;
    const size_t flat = ((size_t)(sg * 3 + c)) * 2048 + (lgk * 16 + lrq) * 32 + t * 4 + j;
    const size_t hstride = (size_t)24 * 3 * 2048;
#pragma unroll
    for (int h = 0; h < NHEAD; h++) {
        float p = z0 * bw[c0 * NHEAD + h] + z1 * bw[(c0 + 1) * NHEAD + h];
#pragma unroll
        for (int o = 32; o; o >>= 1) p += __shfl_xor(p, o);
        if (lane == 0) bias_perm[flat + h * hstride] = p;
    }
}

// ---------------------------------------------------------------------------
// Kernel 2: transpose weights to [out][in] bf16. order: Wq,Wk,Wv,Wg,Wo
// ---------------------------------------------------------------------------
__global__ __launch_bounds__(256) void k_wt(
    const float* __restrict__ Wq, const float* __restrict__ Wk,
    const float* __restrict__ Wv, const float* __restrict__ Wg,
    const float* __restrict__ Wo, __hip_bfloat16* __restrict__ WT)
{
    const int m = blockIdx.y;
    const float* src = (m == 0) ? Wq : (m == 1) ? Wk : (m == 2) ? Wv : (m == 3) ? Wg : Wo;
    const int idx = blockIdx.x * 256 + threadIdx.x;
    const int in = idx >> 7, out = idx & 127;
    WT[m * 16384 + out * 128 + in] = __float2bfloat16(src[idx]);
}

// ---------------------------------------------------------------------------
// Kernel 3: fused projections + flash attention (SWAPPED QK^T), one block per
// (row i, head h).  512 thr = 8 waves, 3 q-strips/wave, 3 key-chunks of 128.
// S^T = mfma32(K,Q): lane owns q=lr -> scalar m/l, 2-shuffle reductions.
// PV via 16x16x16: P-frag == lane's own sacc (no LDS round-trip, no Ps).
// LDS = 29,184 B.
// ---------------------------------------------------------------------------
__global__ __launch_bounds__(512, 2) void k_attn(
    const __hip_bfloat16* __restrict__ Zb,   // [N*N][128]
    const __hip_bfloat16* __restrict__ WT,   // 5 x [128][128] (out-major)
    const float* __restrict__ bias_perm,     // permuted, see k_ln
    __hip_bfloat16* __restrict__ Ob)         // [N*N][128]
{
    __shared__ short Ks[KCH * 40];           // [128][40]
    __shared__ short Vt[CDIM * VSTR];        // [32][136] (V transposed)
    __shared__ short Qst[8][16 * 40];        // per-wave Q staging tile

    const int i = blockIdx.x, h = blockIdx.y;
    const int tid = threadIdx.x, wave = tid >> 6, lane = tid & 63;
    const int lr = lane & 15, lg = lane >> 4;
    const short* Zrow = (const short*)Zb + (size_t)i * NSEQ * DPAIR;
    const short* WQ = (const short*)WT + 0 * 16384 + (h * CDIM) * DPAIR;
    const short* WK = (const short*)WT + 1 * 16384 + (h * CDIM) * DPAIR;
    const short* WV = (const short*)WT + 2 * 16384 + (h * CDIM) * DPAIR;

    // ---- Q phase: this wave's 3 q-strips -> register B-fragments ----
    bf16x8 qreg[3];
    short* Qw = Qst[wave];
#pragma unroll
    for (int s = 0; s < 3; ++s) {
        const int q0 = wave * 48 + s * 16;
        f32x4 a0 = {0.f, 0.f, 0.f, 0.f}, a1 = {0.f, 0.f, 0.f, 0.f};
#pragma unroll
        for (int ks = 0; ks < 4; ks++) {
            bf16x8 afr = *(const bf16x8*)(Zrow + (q0 + lr) * DPAIR + ks * 32 + lg * 8);
            bf16x8 b0 = *(const bf16x8*)(WQ + lr * DPAIR + ks * 32 + lg * 8);
            bf16x8 b1 = *(const bf16x8*)(WQ + (16 + lr) * DPAIR + ks * 32 + lg * 8);
            a0 = __builtin_amdgcn_mfma_f32_16x16x32_bf16(afr, b0, a0, 0, 0, 0);
            a1 = __builtin_amdgcn_mfma_f32_16x16x32_bf16(afr, b1, a1, 0, 0, 0);
        }
#pragma unroll
        for (int j = 0; j < 4; j++) {
            Qw[(lg * 4 + j) * 40 + lr]      = f2b(a0[j]);
            Qw[(lg * 4 + j) * 40 + 16 + lr] = f2b(a1[j]);
        }
        asm volatile("s_waitcnt lgkmcnt(0)" ::: "memory");
        qreg[s] = *(const bf16x8*)(Qw + lr * 40 + lg * 8);
        asm volatile("" ::: "memory");
    }

    // ---- online-softmax state (scalar per lane: q = lr) ----
    float m_run[3], l_run[3];
    f32x4 oacc[3][2];
#pragma unroll
    for (int s = 0; s < 3; s++) {
        m_run[s] = -1e30f; l_run[s] = 0.f;
        oacc[s][0] = (f32x4){0.f, 0.f, 0.f, 0.f};
        oacc[s][1] = (f32x4){0.f, 0.f, 0.f, 0.f};
    }

    const float scale = 0.17677669529663689f;   // 1/sqrt(32)

    for (int c = 0; c < 3; c++) {
        __syncthreads();   // protect Ks/Vt while prior chunk in use
        // ---- K/V projection for keys [c*128, c*128+128): 1 tile per wave ----
        {
            const int jt = wave;
            const int jg = c * KCH + jt * 16;
            bf16x8 afr[4];
#pragma unroll
            for (int ks = 0; ks < 4; ks++)
                afr[ks] = *(const bf16x8*)(Zrow + (jg + lr) * DPAIR + ks * 32 + lg * 8);
#pragma unroll
            for (int mat = 0; mat < 2; mat++) {
                const short* WB = mat ? WV : WK;
#pragma unroll
                for (int nt = 0; nt < 2; nt++) {
                    f32x4 acc = {0.f, 0.f, 0.f, 0.f};
#pragma unroll
                    for (int ks = 0; ks < 4; ks++) {
                        bf16x8 bfr = *(const bf16x8*)(WB + (nt * 16 + lr) * DPAIR + ks * 32 + lg * 8);
                        acc = __builtin_amdgcn_mfma_f32_16x16x32_bf16(afr[ks], bfr, acc, 0, 0, 0);
                    }
#pragma unroll
                    for (int j = 0; j < 4; j++) {
                        const int rl = jt * 16 + lg * 4 + j;
                        const int col = nt * 16 + lr;
                        const short v = f2b(acc[j]);
                        if (mat == 0) Ks[rl * 40 + col] = v;
                        else          Vt[col * VSTR + rl] = v;
                    }
                }
            }
        }
        __syncthreads();

        // ---- attention over this chunk, 3 strips per wave ----
#pragma unroll
        for (int s = 0; s < 3; s++) {
            const int sg = wave * 3 + s;
            // bias loads first (hide L2 latency under QK MFMAs)
            const float* bbase = bias_perm + ((size_t)(h * 24 + sg) * 3 + c) * 2048 + lane * 32;
            float4 bt[8];
#pragma unroll
            for (int t = 0; t < 8; t++) bt[t] = *(const float4*)(bbase + t * 4);

            // S^T = mfma32(A=K, B=Q): lane holds S[k=16t+4lg+j][q=lr]
            f32x4 sacc[8];
            __builtin_amdgcn_s_setprio(1);
#pragma unroll
            for (int t = 0; t < 8; t++) {
                bf16x8 kfr = *(const bf16x8*)(Ks + (t * 16 + lr) * 40 + lg * 8);
                f32x4 z = {0.f, 0.f, 0.f, 0.f};
                sacc[t] = __builtin_amdgcn_mfma_f32_16x16x32_bf16(kfr, qreg[s], z, 0, 0, 0);
            }
            __builtin_amdgcn_s_setprio(0);

            float pm = m_run[s];
#pragma unroll
            for (int t = 0; t < 8; t++) {
                const float* btp = (const float*)&bt[t];
#pragma unroll
                for (int j = 0; j < 4; j++) {
                    const float v = sacc[t][j] * scale + btp[j];
                    sacc[t][j] = v;
                    pm = fmaxf(pm, v);
                }
            }
            pm = fmaxf(pm, __shfl_xor(pm, 16));
            pm = fmaxf(pm, __shfl_xor(pm, 32));

            float sum = 0.f;
#pragma unroll
            for (int t = 0; t < 8; t++) {
#pragma unroll
                for (int j = 0; j < 4; j++) {
                    const float p = __expf(sacc[t][j] - pm);
                    sacc[t][j] = p;
                    sum += p;
                }
            }
            sum += __shfl_xor(sum, 16);
            sum += __shfl_xor(sum, 32);

            const float fs = __expf(m_run[s] - pm);      // 0 at c==0
            l_run[s] = l_run[s] * fs + sum;
            m_run[s] = pm;
            oacc[s][0] *= fs;
            oacc[s][1] *= fs;

            // pack P fragments (lane-local!): pf[t] = bf16(sacc[t][0..3])
            bf16x4 pf[8];
#pragma unroll
            for (int t = 0; t < 8; t++) {
                bf16x4 v;
                v[0] = f2b(sacc[t][0]); v[1] = f2b(sacc[t][1]);
                v[2] = f2b(sacc[t][2]); v[3] = f2b(sacc[t][3]);
                pf[t] = v;
            }

            // O^T += mfma16(A=V^T, B=P) : 16 MFMAs, no LDS for P
            __builtin_amdgcn_s_setprio(1);
#pragma unroll
            for (int t = 0; t < 8; t++) {
                bf16x4 v0 = *(const bf16x4*)(Vt + lr * VSTR + t * 16 + lg * 4);
                bf16x4 v1 = *(const bf16x4*)(Vt + (16 + lr) * VSTR + t * 16 + lg * 4);
                mfma16(oacc[s][0], v0, pf[t]);
                mfma16(oacc[s][1], v1, pf[t]);
            }
            __builtin_amdgcn_s_setprio(0);
        }
    }

    // MFMA -> VALU D-read safety for the last PV cluster
    asm volatile("s_nop 7\n\ts_nop 7" ::: "memory");

    // ---- store O: lane has O[q=q0+lr][c=h*32+nt*16+lg*4+j] ----
#pragma unroll
    for (int s = 0; s < 3; s++) {
        const int q0 = wave * 48 + s * 16;
        const float invl = 1.f / l_run[s];
        const size_t row = (size_t)i * NSEQ + q0 + lr;
#pragma unroll
        for (int nt = 0; nt < 2; nt++) {
            bf16x4 o;
#pragma unroll
            for (int j = 0; j < 4; j++) o[j] = f2b(oacc[s][nt][j] * invl);
            *(bf16x4*)((short*)Ob + row * DPAIR + h * CDIM + nt * 16 + lg * 4) = o;
        }
    }
}

// ---------------------------------------------------------------------------
// Kernel 4: gate + output projection + residual.  64 positions per block.
// ---------------------------------------------------------------------------
__global__ __launch_bounds__(256) void k_out(
    const float* __restrict__ Zraw,
    const __hip_bfloat16* __restrict__ Zb,
    const __hip_bfloat16* __restrict__ Ob,
    const __hip_bfloat16* __restrict__ WT,
    const float* __restrict__ bg,
    const float* __restrict__ out_bias,
    float* __restrict__ out)
{
    __shared__ short Zt[64 * OSTR];
    __shared__ short GOt[64 * OSTR];
    const int pos0 = blockIdx.x * 64;
    const int tid = threadIdx.x, wave = tid >> 6, lane = tid & 63;
    const int lr = lane & 15, lg = lane >> 4;

#pragma unroll
    for (int it = 0; it < 4; ++it) {
        const int cidx = tid + 256 * it;
        const int row = cidx >> 4, cc = (cidx & 15) * 8;
        *(bf16x8*)(Zt + row * OSTR + cc) =
            *(const bf16x8*)((const short*)Zb + (size_t)(pos0 + row) * DPAIR + cc);
    }
    __syncthreads();

    const short* WgT = (const short*)WT + 3 * 16384;
    const short* WoT = (const short*)WT + 4 * 16384;
    const int m0 = wave * 16;

    bf16x8 afr[4];
#pragma unroll
    for (int ks = 0; ks < 4; ks++)
        afr[ks] = *(const bf16x8*)(Zt + (m0 + lr) * OSTR + ks * 32 + lg * 8);
#pragma unroll
    for (int nt = 0; nt < 8; nt++) {
        f32x4 acc = {0.f, 0.f, 0.f, 0.f};
#pragma unroll
        for (int ks = 0; ks < 4; ks++) {
            bf16x8 bfr = *(const bf16x8*)(WgT + (nt * 16 + lr) * DPAIR + ks * 32 + lg * 8);
            acc = __builtin_amdgcn_mfma_f32_16x16x32_bf16(afr[ks], bfr, acc, 0, 0, 0);
        }
        const int col = nt * 16 + lr;
        const float bgv = bg[col];
#pragma unroll
        for (int j = 0; j < 4; j++) {
            const int row = m0 + lg * 4 + j;
            const float g = 1.f / (1.f + __expf(-(acc[j] + bgv)));
            const float ov = b2f(((const short*)Ob)[(size_t)(pos0 + row) * DPAIR + col]);
            GOt[row * OSTR + col] = f2b(g * ov);
        }
    }
    __syncthreads();

#pragma unroll
    for (int ks = 0; ks < 4; ks++)
        afr[ks] = *(const bf16x8*)(GOt + (m0 + lr) * OSTR + ks * 32 + lg * 8);
#pragma unroll
    for (int nt = 0; nt < 8; nt++) {
        f32x4 acc = {0.f, 0.f, 0.f, 0.f};
#pragma unroll
        for (int ks = 0; ks < 4; ks++) {
            bf16x8 bfr = *(const bf16x8*)(WoT + (nt * 16 + lr) * DPAIR + ks * 32 + lg * 8);
            acc = __builtin_amdgcn_mfma_f32_16x16x32_bf16(afr[ks], bfr, acc, 0, 0, 0);
        }
        const int col = nt * 16 + lr;
        const float ob = out_bias[col];
#pragma unroll
        for (int j = 0; j < 4; j++) {
            const size_t idx = (size_t)(pos0 + m0 + lg * 4 + j) * DPAIR + col;
            out[idx] = Zraw[idx] + acc[j] + ob;
        }
    }
}

// ---------------------------------------------------------------------------
extern "C" void kernel_launch(void* const* d_in, const int* in_sizes, int n_in,
                              void* d_out, int out_size, void* d_ws, size_t ws_size,
                              hipStream_t stream)
{
    const float* Zraw     = (const float*)d_in[0];
    const float* gamma    = (const float*)d_in[1];
    const float* beta     = (const float*)d_in[2];
    const float* bw       = (const float*)d_in[3];
    const float* Wq       = (const float*)d_in[4];
    const float* Wk       = (const float*)d_in[5];
    const float* Wv       = (const float*)d_in[6];
    const float* Wg       = (const float*)d_in[7];
    const float* bg       = (const float*)d_in[8];
    const float* Wo       = (const float*)d_in[9];
    const float* out_bias = (const float*)d_in[10];

    char* ws = (char*)d_ws;
    const size_t zbytes = (size_t)NSEQ * NSEQ * DPAIR * 2;
    __hip_bfloat16* Zb        = (__hip_bfloat16*)ws;
    __hip_bfloat16* Ob        = (__hip_bfloat16*)(ws + zbytes);
    float*          bias_perm = (float*)(ws + 2 * zbytes);
    __hip_bfloat16* WT        = (__hip_bfloat16*)(ws + 2 * zbytes + (size_t)NHEAD * NSEQ * NSEQ * 4);

    k_ln<<<NSEQ * NSEQ / 4, 256, 0, stream>>>(Zraw, gamma, beta, bw, Zb, bias_perm);
    k_wt<<<dim3(64, 5), 256, 0, stream>>>(Wq, Wk, Wv, Wg, Wo, WT);
    k_attn<<<dim3(NSEQ, NHEAD), 512, 0, stream>>>(Zb, WT, bias_perm, Ob);
    k_out<<<NSEQ * NSEQ / 64, 256, 0, stream>>>(Zraw, Zb, Ob, WT, bg, out_bias, (float*)d_out);
}